// Round 1
// baseline (998.377 us; speedup 1.0000x reference)
//
#include <hip/hip_runtime.h>

// ---------------------------------------------------------------------------
// GraphConv x3 + FC on MI355X.
// Strategy: CSR build per call (no float atomics), bf16 activations/weights,
// MFMA 16x16x32 bf16 for all GEMMs (fp32 accum), fused rel+root GEMM.
// ---------------------------------------------------------------------------

typedef short bf16x8 __attribute__((ext_vector_type(8)));
typedef float f32x4 __attribute__((ext_vector_type(4)));

__device__ inline float bf2f(unsigned short u) {
    union { unsigned int i; float f; } v; v.i = ((unsigned int)u) << 16; return v.f;
}
__device__ inline unsigned short f2bf(float f) {
    union { float f; unsigned int i; } v; v.f = f;
    unsigned int r = v.i + 0x7FFFu + ((v.i >> 16) & 1u);   // round-to-nearest-even
    return (unsigned short)(r >> 16);
}

// ---- dtype conversion ------------------------------------------------------
__global__ void f2bf_kernel(const float* __restrict__ in,
                            unsigned short* __restrict__ out, int n) {
    int i = blockIdx.x * 256 + threadIdx.x;
    if (i < n) out[i] = f2bf(in[i]);
}

// ---- CSR build -------------------------------------------------------------
__global__ void degree_kernel(const int* __restrict__ dst, int* __restrict__ deg, int e) {
    int i = blockIdx.x * 256 + threadIdx.x;
    if (i < e) atomicAdd(&deg[dst[i]], 1);
}

__global__ void scan_partial(const int* __restrict__ deg, int* __restrict__ excl,
                             int* __restrict__ bsums, int n) {
    __shared__ int buf[256];
    int t = threadIdx.x, i = blockIdx.x * 256 + t;
    int v = (i < n) ? deg[i] : 0;
    int x = v; buf[t] = v; __syncthreads();
    for (int o = 1; o < 256; o <<= 1) {
        int y = (t >= o) ? buf[t - o] : 0;
        __syncthreads();
        x += y; buf[t] = x;
        __syncthreads();
    }
    if (i < n) excl[i] = x - v;            // block-local exclusive
    if (t == 255) bsums[blockIdx.x] = x;   // block total
}

__global__ void scan_bsums(const int* __restrict__ bsums, int* __restrict__ boffs, int nb) {
    __shared__ int buf[512];
    int t = threadIdx.x;
    int v = (t < nb) ? bsums[t] : 0;
    int x = v; buf[t] = v; __syncthreads();
    for (int o = 1; o < 512; o <<= 1) {
        int y = (t >= o) ? buf[t - o] : 0;
        __syncthreads();
        x += y; buf[t] = x;
        __syncthreads();
    }
    if (t < nb) boffs[t] = x - v;          // exclusive block offsets
}

__global__ void finalize_scan(const int* __restrict__ excl, const int* __restrict__ boffs,
                              int* __restrict__ start, int* __restrict__ cursor, int n) {
    int i = blockIdx.x * 256 + threadIdx.x;
    if (i < n) { int s = excl[i] + boffs[blockIdx.x]; start[i] = s; cursor[i] = s; }
}

__global__ void fill_kernel(const int* __restrict__ src, const int* __restrict__ dst,
                            int* __restrict__ cursor, int* __restrict__ csr, int e) {
    int i = blockIdx.x * 256 + threadIdx.x;
    if (i < e) {
        int p = atomicAdd(&cursor[dst[i]], 1);
        csr[p] = src[i];
    }
}

// ---- neighbor aggregation: agg[i,:] = sum_{j in N(i)} x[j,:] ---------------
// one block (128 threads) per node; each edge row read is 256 B coalesced.
__global__ void agg_kernel(const unsigned short* __restrict__ xb, const int* __restrict__ csr,
                           const int* __restrict__ start, const int* __restrict__ deg,
                           unsigned short* __restrict__ aggb, int n) {
    int i = blockIdx.x;
    int f = threadIdx.x;
    int s0 = start[i];
    int d  = deg[i];
    float acc = 0.f;
    for (int e2 = 0; e2 < d; e2++) {
        int s = csr[s0 + e2];
        acc += bf2f(xb[(size_t)s * 128 + f]);
    }
    aggb[(size_t)i * 128 + f] = f2bf(acc);
}

// ---- fused GEMM: out = A1 @ W1^T (+ A2 @ W2^T) + bias ----------------------
// MFMA 16x16x32 bf16. A[m][k]: m=lane&15, k=quad*8+j (contiguous 8 bf16).
// B[k][n] = W[n][k]: n=lane&15, k=quad*8+j  -> W rows load contiguously.
// C/D: col=lane&15, row=quad*4+reg.
template <int NOUT, bool DUAL, bool F32OUT>
__global__ __launch_bounds__(256) void gemm_kernel(
    const unsigned short* __restrict__ A1, const unsigned short* __restrict__ A2,
    const unsigned short* __restrict__ W1, const unsigned short* __restrict__ W2,
    const float* __restrict__ bias,
    unsigned short* __restrict__ outb, float* __restrict__ outf, int n) {
    int wave = threadIdx.x >> 6;
    int lane = threadIdx.x & 63;
    int m    = lane & 15;
    int quad = lane >> 4;
    int row0 = blockIdx.x * 64 + wave * 16;
    int arow = row0 + m; if (arow >= n) arow = n - 1;   // clamp; store is guarded
    size_t abase = (size_t)arow * 128 + quad * 8;

    bf16x8 a1[4], a2[4];
#pragma unroll
    for (int kk = 0; kk < 4; kk++) {
        a1[kk] = *(const bf16x8*)(A1 + abase + kk * 32);
        if (DUAL) a2[kk] = *(const bf16x8*)(A2 + abase + kk * 32);
    }

#pragma unroll
    for (int t = 0; t < NOUT / 16; t++) {
        int o = t * 16 + m;
        size_t wbase = (size_t)o * 128 + quad * 8;
        f32x4 acc = {0.f, 0.f, 0.f, 0.f};
#pragma unroll
        for (int kk = 0; kk < 4; kk++) {
            bf16x8 b1 = *(const bf16x8*)(W1 + wbase + kk * 32);
            acc = __builtin_amdgcn_mfma_f32_16x16x32_bf16(a1[kk], b1, acc, 0, 0, 0);
        }
        if (DUAL) {
#pragma unroll
            for (int kk = 0; kk < 4; kk++) {
                bf16x8 b2 = *(const bf16x8*)(W2 + wbase + kk * 32);
                acc = __builtin_amdgcn_mfma_f32_16x16x32_bf16(a2[kk], b2, acc, 0, 0, 0);
            }
        }
        float bv = bias[o];
#pragma unroll
        for (int r = 0; r < 4; r++) {
            int orow = row0 + quad * 4 + r;
            if (orow < n) {
                float val = acc[r] + bv;
                if (F32OUT) outf[(size_t)orow * NOUT + o] = val;
                else        outb[(size_t)orow * NOUT + o] = f2bf(val);
            }
        }
    }
}

// ---------------------------------------------------------------------------
extern "C" void kernel_launch(void* const* d_in, const int* in_sizes, int n_in,
                              void* d_out, int out_size, void* d_ws, size_t ws_size,
                              hipStream_t stream) {
    const float* x      = (const float*)d_in[0];
    const int*   ei     = (const int*)d_in[1];
    const float* W_rel  = (const float*)d_in[2];
    const float* b_rel  = (const float*)d_in[3];
    const float* W_root = (const float*)d_in[4];
    const float* fc_w   = (const float*)d_in[5];
    const float* fc_b   = (const float*)d_in[6];

    const int n = in_sizes[0] / 128;      // 100000
    const int e = in_sizes[1] / 2;        // 1600000
    const int* src = ei;
    const int* dst = ei + e;
    const int L = in_sizes[2] / (128 * 128);  // 3

    // workspace carve-up (256 B aligned)
    char* p = (char*)d_ws;
    auto take = [&](size_t bytes) -> void* {
        void* r = (void*)p;
        p += (bytes + 255) & ~(size_t)255;
        return r;
    };
    unsigned short* x_bf   = (unsigned short*)take((size_t)n * 128 * 2);
    unsigned short* y_bf   = (unsigned short*)take((size_t)n * 128 * 2);
    unsigned short* agg_bf = (unsigned short*)take((size_t)n * 128 * 2);
    unsigned short* Wr_bf  = (unsigned short*)take((size_t)L * 128 * 128 * 2);
    unsigned short* Wo_bf  = (unsigned short*)take((size_t)L * 128 * 128 * 2);
    unsigned short* fc_bf  = (unsigned short*)take((size_t)64 * 128 * 2);
    int* deg    = (int*)take((size_t)n * 4);
    int* excl   = (int*)take((size_t)n * 4);
    int* bsums  = (int*)take(512 * 4);
    int* boffs  = (int*)take(512 * 4);
    int* start  = (int*)take((size_t)n * 4);
    int* cursor = (int*)take((size_t)n * 4);
    int* csr    = (int*)take((size_t)e * 4);

    const int nb = (n + 255) / 256;       // 391 scan blocks

    // conversions
    hipMemsetAsync(deg, 0, (size_t)n * 4, stream);
    f2bf_kernel<<<(n * 128 + 255) / 256, 256, 0, stream>>>(x, x_bf, n * 128);
    f2bf_kernel<<<(L * 128 * 128 + 255) / 256, 256, 0, stream>>>(W_rel, Wr_bf, L * 128 * 128);
    f2bf_kernel<<<(L * 128 * 128 + 255) / 256, 256, 0, stream>>>(W_root, Wo_bf, L * 128 * 128);
    f2bf_kernel<<<(64 * 128 + 255) / 256, 256, 0, stream>>>(fc_w, fc_bf, 64 * 128);

    // CSR build
    degree_kernel<<<(e + 255) / 256, 256, 0, stream>>>(dst, deg, e);
    scan_partial<<<nb, 256, 0, stream>>>(deg, excl, bsums, n);
    scan_bsums<<<1, 512, 0, stream>>>(bsums, boffs, nb);
    finalize_scan<<<nb, 256, 0, stream>>>(excl, boffs, start, cursor, n);
    fill_kernel<<<(e + 255) / 256, 256, 0, stream>>>(src, dst, cursor, csr, e);

    // layers
    unsigned short* cur = x_bf;
    unsigned short* nxt = y_bf;
    for (int l = 0; l < L; l++) {
        agg_kernel<<<n, 128, 0, stream>>>(cur, csr, start, deg, agg_bf, n);
        gemm_kernel<128, true, false><<<(n + 63) / 64, 256, 0, stream>>>(
            agg_bf, cur, Wr_bf + (size_t)l * 128 * 128, Wo_bf + (size_t)l * 128 * 128,
            b_rel + (size_t)l * 128, nxt, nullptr, n);
        unsigned short* t2 = cur; cur = nxt; nxt = t2;
    }

    // final FC -> f32 out
    gemm_kernel<64, false, true><<<(n + 63) / 64, 256, 0, stream>>>(
        cur, nullptr, fc_bf, nullptr, fc_b, nullptr, (float*)d_out, n);
}

// Round 2
// 720.184 us; speedup vs baseline: 1.3863x; 1.3863x over previous
//
#include <hip/hip_runtime.h>

// ---------------------------------------------------------------------------
// GraphConv x3 + FC on MI355X.
// CSR build per call (no float atomics), bf16 activations/weights,
// MFMA 16x16x32 bf16 for all GEMMs (fp32 accum), fused rel+root GEMM.
// R2: agg_kernel rewritten — wave/node, 4 edges in flight, 16B vector loads.
// ---------------------------------------------------------------------------

typedef short bf16x8 __attribute__((ext_vector_type(8)));
typedef float f32x4 __attribute__((ext_vector_type(4)));

__device__ inline float bf2f(unsigned short u) {
    union { unsigned int i; float f; } v; v.i = ((unsigned int)u) << 16; return v.f;
}
__device__ inline unsigned short f2bf(float f) {
    union { float f; unsigned int i; } v; v.f = f;
    unsigned int r = v.i + 0x7FFFu + ((v.i >> 16) & 1u);   // round-to-nearest-even
    return (unsigned short)(r >> 16);
}

// ---- dtype conversion ------------------------------------------------------
__global__ void f2bf_kernel(const float* __restrict__ in,
                            unsigned short* __restrict__ out, int n) {
    int i = blockIdx.x * 256 + threadIdx.x;
    if (i < n) out[i] = f2bf(in[i]);
}

// ---- CSR build -------------------------------------------------------------
__global__ void degree_kernel(const int* __restrict__ dst, int* __restrict__ deg, int e) {
    int i = blockIdx.x * 256 + threadIdx.x;
    if (i < e) atomicAdd(&deg[dst[i]], 1);
}

__global__ void scan_partial(const int* __restrict__ deg, int* __restrict__ excl,
                             int* __restrict__ bsums, int n) {
    __shared__ int buf[256];
    int t = threadIdx.x, i = blockIdx.x * 256 + t;
    int v = (i < n) ? deg[i] : 0;
    int x = v; buf[t] = v; __syncthreads();
    for (int o = 1; o < 256; o <<= 1) {
        int y = (t >= o) ? buf[t - o] : 0;
        __syncthreads();
        x += y; buf[t] = x;
        __syncthreads();
    }
    if (i < n) excl[i] = x - v;            // block-local exclusive
    if (t == 255) bsums[blockIdx.x] = x;   // block total
}

__global__ void scan_bsums(const int* __restrict__ bsums, int* __restrict__ boffs, int nb) {
    __shared__ int buf[512];
    int t = threadIdx.x;
    int v = (t < nb) ? bsums[t] : 0;
    int x = v; buf[t] = v; __syncthreads();
    for (int o = 1; o < 512; o <<= 1) {
        int y = (t >= o) ? buf[t - o] : 0;
        __syncthreads();
        x += y; buf[t] = x;
        __syncthreads();
    }
    if (t < nb) boffs[t] = x - v;          // exclusive block offsets
}

__global__ void finalize_scan(const int* __restrict__ excl, const int* __restrict__ boffs,
                              int* __restrict__ start, int* __restrict__ cursor, int n) {
    int i = blockIdx.x * 256 + threadIdx.x;
    if (i < n) { int s = excl[i] + boffs[blockIdx.x]; start[i] = s; cursor[i] = s; }
}

__global__ void fill_kernel(const int* __restrict__ src, const int* __restrict__ dst,
                            int* __restrict__ cursor, int* __restrict__ csr, int e) {
    int i = blockIdx.x * 256 + threadIdx.x;
    if (i < e) {
        int p = atomicAdd(&cursor[dst[i]], 1);
        csr[p] = src[i];
    }
}

// ---- neighbor aggregation: agg[i,:] = sum_{j in N(i)} x[j,:] ---------------
// one WAVE per node. 4 lane-groups of 16; lane loads bf16x8 (16 B) so one
// group covers a 256 B row; 4 edge rows in flight per iteration (x2 unroll).
// Cross-group reduce via shfl_xor(16/32); group 0 stores packed 16 B.
__global__ __launch_bounds__(256) void agg_kernel(
    const unsigned short* __restrict__ xb, const int* __restrict__ csr,
    const int* __restrict__ start, const int* __restrict__ deg,
    unsigned short* __restrict__ aggb, int n) {
    int node = blockIdx.x * 4 + (threadIdx.x >> 6);
    if (node >= n) return;
    int lane = threadIdx.x & 63;
    int g    = lane >> 4;      // edge slot 0..3
    int fl   = lane & 15;      // feature chunk: 8 bf16 = 16 B

    int s0 = start[node];
    int d  = deg[node];

    float acc[8];
#pragma unroll
    for (int j = 0; j < 8; j++) acc[j] = 0.f;

#pragma unroll 2
    for (int e0 = 0; e0 < d; e0 += 4) {
        int idx = e0 + g;
        if (idx < d) {
            int s = csr[s0 + idx];
            bf16x8 v = *(const bf16x8*)(xb + (size_t)s * 128 + fl * 8);
#pragma unroll
            for (int j = 0; j < 8; j++) acc[j] += bf2f((unsigned short)v[j]);
        }
    }

#pragma unroll
    for (int j = 0; j < 8; j++) {
        acc[j] += __shfl_xor(acc[j], 16);
        acc[j] += __shfl_xor(acc[j], 32);
    }

    if (g == 0) {
        bf16x8 o;
#pragma unroll
        for (int j = 0; j < 8; j++) o[j] = (short)f2bf(acc[j]);
        *(bf16x8*)(aggb + (size_t)node * 128 + fl * 8) = o;
    }
}

// ---- fused GEMM: out = A1 @ W1^T (+ A2 @ W2^T) + bias ----------------------
// MFMA 16x16x32 bf16. A[m][k]: m=lane&15, k=quad*8+j (contiguous 8 bf16).
// B[k][n] = W[n][k]: n=lane&15, k=quad*8+j  -> W rows load contiguously.
// C/D: col=lane&15, row=quad*4+reg.
template <int NOUT, bool DUAL, bool F32OUT>
__global__ __launch_bounds__(256) void gemm_kernel(
    const unsigned short* __restrict__ A1, const unsigned short* __restrict__ A2,
    const unsigned short* __restrict__ W1, const unsigned short* __restrict__ W2,
    const float* __restrict__ bias,
    unsigned short* __restrict__ outb, float* __restrict__ outf, int n) {
    int wave = threadIdx.x >> 6;
    int lane = threadIdx.x & 63;
    int m    = lane & 15;
    int quad = lane >> 4;
    int row0 = blockIdx.x * 64 + wave * 16;
    int arow = row0 + m; if (arow >= n) arow = n - 1;   // clamp; store is guarded
    size_t abase = (size_t)arow * 128 + quad * 8;

    bf16x8 a1[4], a2[4];
#pragma unroll
    for (int kk = 0; kk < 4; kk++) {
        a1[kk] = *(const bf16x8*)(A1 + abase + kk * 32);
        if (DUAL) a2[kk] = *(const bf16x8*)(A2 + abase + kk * 32);
    }

#pragma unroll
    for (int t = 0; t < NOUT / 16; t++) {
        int o = t * 16 + m;
        size_t wbase = (size_t)o * 128 + quad * 8;
        f32x4 acc = {0.f, 0.f, 0.f, 0.f};
#pragma unroll
        for (int kk = 0; kk < 4; kk++) {
            bf16x8 b1 = *(const bf16x8*)(W1 + wbase + kk * 32);
            acc = __builtin_amdgcn_mfma_f32_16x16x32_bf16(a1[kk], b1, acc, 0, 0, 0);
        }
        if (DUAL) {
#pragma unroll
            for (int kk = 0; kk < 4; kk++) {
                bf16x8 b2 = *(const bf16x8*)(W2 + wbase + kk * 32);
                acc = __builtin_amdgcn_mfma_f32_16x16x32_bf16(a2[kk], b2, acc, 0, 0, 0);
            }
        }
        float bv = bias[o];
#pragma unroll
        for (int r = 0; r < 4; r++) {
            int orow = row0 + quad * 4 + r;
            if (orow < n) {
                float val = acc[r] + bv;
                if (F32OUT) outf[(size_t)orow * NOUT + o] = val;
                else        outb[(size_t)orow * NOUT + o] = f2bf(val);
            }
        }
    }
}

// ---------------------------------------------------------------------------
extern "C" void kernel_launch(void* const* d_in, const int* in_sizes, int n_in,
                              void* d_out, int out_size, void* d_ws, size_t ws_size,
                              hipStream_t stream) {
    const float* x      = (const float*)d_in[0];
    const int*   ei     = (const int*)d_in[1];
    const float* W_rel  = (const float*)d_in[2];
    const float* b_rel  = (const float*)d_in[3];
    const float* W_root = (const float*)d_in[4];
    const float* fc_w   = (const float*)d_in[5];
    const float* fc_b   = (const float*)d_in[6];

    const int n = in_sizes[0] / 128;      // 100000
    const int e = in_sizes[1] / 2;        // 1600000
    const int* src = ei;
    const int* dst = ei + e;
    const int L = in_sizes[2] / (128 * 128);  // 3

    // workspace carve-up (256 B aligned)
    char* p = (char*)d_ws;
    auto take = [&](size_t bytes) -> void* {
        void* r = (void*)p;
        p += (bytes + 255) & ~(size_t)255;
        return r;
    };
    unsigned short* x_bf   = (unsigned short*)take((size_t)n * 128 * 2);
    unsigned short* y_bf   = (unsigned short*)take((size_t)n * 128 * 2);
    unsigned short* agg_bf = (unsigned short*)take((size_t)n * 128 * 2);
    unsigned short* Wr_bf  = (unsigned short*)take((size_t)L * 128 * 128 * 2);
    unsigned short* Wo_bf  = (unsigned short*)take((size_t)L * 128 * 128 * 2);
    unsigned short* fc_bf  = (unsigned short*)take((size_t)64 * 128 * 2);
    int* deg    = (int*)take((size_t)n * 4);
    int* excl   = (int*)take((size_t)n * 4);
    int* bsums  = (int*)take(512 * 4);
    int* boffs  = (int*)take(512 * 4);
    int* start  = (int*)take((size_t)n * 4);
    int* cursor = (int*)take((size_t)n * 4);
    int* csr    = (int*)take((size_t)e * 4);

    const int nb = (n + 255) / 256;       // 391 scan blocks

    // conversions
    hipMemsetAsync(deg, 0, (size_t)n * 4, stream);
    f2bf_kernel<<<(n * 128 + 255) / 256, 256, 0, stream>>>(x, x_bf, n * 128);
    f2bf_kernel<<<(L * 128 * 128 + 255) / 256, 256, 0, stream>>>(W_rel, Wr_bf, L * 128 * 128);
    f2bf_kernel<<<(L * 128 * 128 + 255) / 256, 256, 0, stream>>>(W_root, Wo_bf, L * 128 * 128);
    f2bf_kernel<<<(64 * 128 + 255) / 256, 256, 0, stream>>>(fc_w, fc_bf, 64 * 128);

    // CSR build
    degree_kernel<<<(e + 255) / 256, 256, 0, stream>>>(dst, deg, e);
    scan_partial<<<nb, 256, 0, stream>>>(deg, excl, bsums, n);
    scan_bsums<<<1, 512, 0, stream>>>(bsums, boffs, nb);
    finalize_scan<<<nb, 256, 0, stream>>>(excl, boffs, start, cursor, n);
    fill_kernel<<<(e + 255) / 256, 256, 0, stream>>>(src, dst, cursor, csr, e);

    // layers
    unsigned short* cur = x_bf;
    unsigned short* nxt = y_bf;
    for (int l = 0; l < L; l++) {
        agg_kernel<<<(n + 3) / 4, 256, 0, stream>>>(cur, csr, start, deg, agg_bf, n);
        gemm_kernel<128, true, false><<<(n + 63) / 64, 256, 0, stream>>>(
            agg_bf, cur, Wr_bf + (size_t)l * 128 * 128, Wo_bf + (size_t)l * 128 * 128,
            b_rel + (size_t)l * 128, nxt, nullptr, n);
        unsigned short* t2 = cur; cur = nxt; nxt = t2;
    }

    // final FC -> f32 out
    gemm_kernel<64, false, true><<<(n + 63) / 64, 256, 0, stream>>>(
        cur, nullptr, fc_bf, nullptr, fc_b, nullptr, (float*)d_out, n);
}

// Round 3
// 640.625 us; speedup vs baseline: 1.5584x; 1.1242x over previous
//
#include <hip/hip_runtime.h>

// ---------------------------------------------------------------------------
// GraphConv x3 + FC on MI355X.
// CSR build per call, bf16 activations/weights, MFMA 16x16x32 bf16 GEMMs.
// R3: rank-trick fill (no atomic in scatter pass), agg unroll 4, merged f2bf.
// ---------------------------------------------------------------------------

typedef short bf16x8 __attribute__((ext_vector_type(8)));
typedef float f32x4 __attribute__((ext_vector_type(4)));

__device__ inline float bf2f(unsigned short u) {
    union { unsigned int i; float f; } v; v.i = ((unsigned int)u) << 16; return v.f;
}
__device__ inline unsigned short f2bf(float f) {
    union { float f; unsigned int i; } v; v.f = f;
    unsigned int r = v.i + 0x7FFFu + ((v.i >> 16) & 1u);   // round-to-nearest-even
    return (unsigned short)(r >> 16);
}

// ---- dtype conversion: 4 arrays in one launch ------------------------------
__global__ void f2bf_multi(const float* __restrict__ p0, unsigned short* __restrict__ q0, int n0,
                           const float* __restrict__ p1, unsigned short* __restrict__ q1, int n1,
                           const float* __restrict__ p2, unsigned short* __restrict__ q2, int n2,
                           const float* __restrict__ p3, unsigned short* __restrict__ q3, int n3) {
    int i = blockIdx.x * 256 + threadIdx.x;
    if (i < n0) { q0[i] = f2bf(p0[i]); }
    i -= n0;
    if (i >= 0 && i < n1) { q1[i] = f2bf(p1[i]); }
    i -= n1;
    if (i >= 0 && i < n2) { q2[i] = f2bf(p2[i]); }
    i -= n2;
    if (i >= 0 && i < n3) { q3[i] = f2bf(p3[i]); }
}

// ---- CSR build -------------------------------------------------------------
// pass 1: degree histogram + per-edge rank (old value of counter)
__global__ void degree_rank_kernel(const int* __restrict__ dst, int* __restrict__ deg,
                                   int* __restrict__ rank, int e) {
    int i = blockIdx.x * 256 + threadIdx.x;
    if (i < e) rank[i] = atomicAdd(&deg[dst[i]], 1);
}

__global__ void scan_partial(const int* __restrict__ deg, int* __restrict__ excl,
                             int* __restrict__ bsums, int n) {
    __shared__ int buf[256];
    int t = threadIdx.x, i = blockIdx.x * 256 + t;
    int v = (i < n) ? deg[i] : 0;
    int x = v; buf[t] = v; __syncthreads();
    for (int o = 1; o < 256; o <<= 1) {
        int y = (t >= o) ? buf[t - o] : 0;
        __syncthreads();
        x += y; buf[t] = x;
        __syncthreads();
    }
    if (i < n) excl[i] = x - v;            // block-local exclusive
    if (t == 255) bsums[blockIdx.x] = x;   // block total
}

__global__ void scan_bsums(const int* __restrict__ bsums, int* __restrict__ boffs, int nb) {
    __shared__ int buf[512];
    int t = threadIdx.x;
    int v = (t < nb) ? bsums[t] : 0;
    int x = v; buf[t] = v; __syncthreads();
    for (int o = 1; o < 512; o <<= 1) {
        int y = (t >= o) ? buf[t - o] : 0;
        __syncthreads();
        x += y; buf[t] = x;
        __syncthreads();
    }
    if (t < nb) boffs[t] = x - v;          // exclusive block offsets
}

__global__ void finalize_scan(const int* __restrict__ excl, const int* __restrict__ boffs,
                              int* __restrict__ start, int n) {
    int i = blockIdx.x * 256 + threadIdx.x;
    if (i < n) start[i] = excl[i] + boffs[blockIdx.x];
}

// pass 2: pure scatter store, no atomics — 64 independent lines in flight/wave
__global__ void fill_kernel(const int* __restrict__ src, const int* __restrict__ dst,
                            const int* __restrict__ rank, const int* __restrict__ start,
                            int* __restrict__ csr, int e) {
    int i = blockIdx.x * 256 + threadIdx.x;
    if (i < e) csr[start[dst[i]] + rank[i]] = src[i];
}

// ---- neighbor aggregation: agg[i,:] = sum_{j in N(i)} x[j,:] ---------------
// one WAVE per node; 4 groups x 16 lanes; lane loads bf16x8 (16 B);
// unroll 4 -> up to 16 edge rows in flight per wave.
__global__ __launch_bounds__(256) void agg_kernel(
    const unsigned short* __restrict__ xb, const int* __restrict__ csr,
    const int* __restrict__ start, const int* __restrict__ deg,
    unsigned short* __restrict__ aggb, int n) {
    int node = blockIdx.x * 4 + (threadIdx.x >> 6);
    if (node >= n) return;
    int lane = threadIdx.x & 63;
    int g    = lane >> 4;      // edge slot 0..3
    int fl   = lane & 15;      // feature chunk: 8 bf16 = 16 B

    int s0 = start[node];
    int d  = deg[node];

    float acc[8];
#pragma unroll
    for (int j = 0; j < 8; j++) acc[j] = 0.f;

#pragma unroll 4
    for (int e0 = 0; e0 < d; e0 += 4) {
        int idx = e0 + g;
        if (idx < d) {
            int s = csr[s0 + idx];
            bf16x8 v = *(const bf16x8*)(xb + (size_t)s * 128 + fl * 8);
#pragma unroll
            for (int j = 0; j < 8; j++) acc[j] += bf2f((unsigned short)v[j]);
        }
    }

#pragma unroll
    for (int j = 0; j < 8; j++) {
        acc[j] += __shfl_xor(acc[j], 16);
        acc[j] += __shfl_xor(acc[j], 32);
    }

    if (g == 0) {
        bf16x8 o;
#pragma unroll
        for (int j = 0; j < 8; j++) o[j] = (short)f2bf(acc[j]);
        *(bf16x8*)(aggb + (size_t)node * 128 + fl * 8) = o;
    }
}

// ---- fused GEMM: out = A1 @ W1^T (+ A2 @ W2^T) + bias ----------------------
// MFMA 16x16x32 bf16. A[m][k]: m=lane&15, k=quad*8+j (contiguous 8 bf16).
// B[k][n] = W[n][k]: n=lane&15, k=quad*8+j  -> W rows load contiguously.
// C/D: col=lane&15, row=quad*4+reg.
template <int NOUT, bool DUAL, bool F32OUT>
__global__ __launch_bounds__(256) void gemm_kernel(
    const unsigned short* __restrict__ A1, const unsigned short* __restrict__ A2,
    const unsigned short* __restrict__ W1, const unsigned short* __restrict__ W2,
    const float* __restrict__ bias,
    unsigned short* __restrict__ outb, float* __restrict__ outf, int n) {
    int wave = threadIdx.x >> 6;
    int lane = threadIdx.x & 63;
    int m    = lane & 15;
    int quad = lane >> 4;
    int row0 = blockIdx.x * 64 + wave * 16;
    int arow = row0 + m; if (arow >= n) arow = n - 1;   // clamp; store is guarded
    size_t abase = (size_t)arow * 128 + quad * 8;

    bf16x8 a1[4], a2[4];
#pragma unroll
    for (int kk = 0; kk < 4; kk++) {
        a1[kk] = *(const bf16x8*)(A1 + abase + kk * 32);
        if (DUAL) a2[kk] = *(const bf16x8*)(A2 + abase + kk * 32);
    }

#pragma unroll
    for (int t = 0; t < NOUT / 16; t++) {
        int o = t * 16 + m;
        size_t wbase = (size_t)o * 128 + quad * 8;
        f32x4 acc = {0.f, 0.f, 0.f, 0.f};
#pragma unroll
        for (int kk = 0; kk < 4; kk++) {
            bf16x8 b1 = *(const bf16x8*)(W1 + wbase + kk * 32);
            acc = __builtin_amdgcn_mfma_f32_16x16x32_bf16(a1[kk], b1, acc, 0, 0, 0);
        }
        if (DUAL) {
#pragma unroll
            for (int kk = 0; kk < 4; kk++) {
                bf16x8 b2 = *(const bf16x8*)(W2 + wbase + kk * 32);
                acc = __builtin_amdgcn_mfma_f32_16x16x32_bf16(a2[kk], b2, acc, 0, 0, 0);
            }
        }
        float bv = bias[o];
#pragma unroll
        for (int r = 0; r < 4; r++) {
            int orow = row0 + quad * 4 + r;
            if (orow < n) {
                float val = acc[r] + bv;
                if (F32OUT) outf[(size_t)orow * NOUT + o] = val;
                else        outb[(size_t)orow * NOUT + o] = f2bf(val);
            }
        }
    }
}

// ---------------------------------------------------------------------------
extern "C" void kernel_launch(void* const* d_in, const int* in_sizes, int n_in,
                              void* d_out, int out_size, void* d_ws, size_t ws_size,
                              hipStream_t stream) {
    const float* x      = (const float*)d_in[0];
    const int*   ei     = (const int*)d_in[1];
    const float* W_rel  = (const float*)d_in[2];
    const float* b_rel  = (const float*)d_in[3];
    const float* W_root = (const float*)d_in[4];
    const float* fc_w   = (const float*)d_in[5];
    const float* fc_b   = (const float*)d_in[6];

    const int n = in_sizes[0] / 128;      // 100000
    const int e = in_sizes[1] / 2;        // 1600000
    const int* src = ei;
    const int* dst = ei + e;
    const int L = in_sizes[2] / (128 * 128);  // 3

    // workspace carve-up (256 B aligned)
    char* p = (char*)d_ws;
    auto take = [&](size_t bytes) -> void* {
        void* r = (void*)p;
        p += (bytes + 255) & ~(size_t)255;
        return r;
    };
    unsigned short* x_bf   = (unsigned short*)take((size_t)n * 128 * 2);
    unsigned short* y_bf   = (unsigned short*)take((size_t)n * 128 * 2);
    unsigned short* agg_bf = (unsigned short*)take((size_t)n * 128 * 2);
    unsigned short* Wr_bf  = (unsigned short*)take((size_t)L * 128 * 128 * 2);
    unsigned short* Wo_bf  = (unsigned short*)take((size_t)L * 128 * 128 * 2);
    unsigned short* fc_bf  = (unsigned short*)take((size_t)64 * 128 * 2);
    int* deg    = (int*)take((size_t)n * 4);
    int* excl   = (int*)take((size_t)n * 4);
    int* bsums  = (int*)take(512 * 4);
    int* boffs  = (int*)take(512 * 4);
    int* start  = (int*)take((size_t)n * 4);
    int* rank   = (int*)take((size_t)e * 4);
    int* csr    = (int*)take((size_t)e * 4);

    const int nb = (n + 255) / 256;       // 391 scan blocks

    const int n0 = n * 128, n1 = L * 128 * 128, n2 = L * 128 * 128, n3 = 64 * 128;
    const int ntot = n0 + n1 + n2 + n3;

    // conversions (one launch) + degree/rank
    hipMemsetAsync(deg, 0, (size_t)n * 4, stream);
    f2bf_multi<<<(ntot + 255) / 256, 256, 0, stream>>>(
        x, x_bf, n0, W_rel, Wr_bf, n1, W_root, Wo_bf, n2, fc_w, fc_bf, n3);

    // CSR build
    degree_rank_kernel<<<(e + 255) / 256, 256, 0, stream>>>(dst, deg, rank, e);
    scan_partial<<<nb, 256, 0, stream>>>(deg, excl, bsums, n);
    scan_bsums<<<1, 512, 0, stream>>>(bsums, boffs, nb);
    finalize_scan<<<nb, 256, 0, stream>>>(excl, boffs, start, n);
    fill_kernel<<<(e + 255) / 256, 256, 0, stream>>>(src, dst, rank, start, csr, e);

    // layers
    unsigned short* cur = x_bf;
    unsigned short* nxt = y_bf;
    for (int l = 0; l < L; l++) {
        agg_kernel<<<(n + 3) / 4, 256, 0, stream>>>(cur, csr, start, deg, agg_bf, n);
        gemm_kernel<128, true, false><<<(n + 63) / 64, 256, 0, stream>>>(
            agg_bf, cur, Wr_bf + (size_t)l * 128 * 128, Wo_bf + (size_t)l * 128 * 128,
            b_rel + (size_t)l * 128, nxt, nullptr, n);
        unsigned short* t2 = cur; cur = nxt; nxt = t2;
    }

    // final FC -> f32 out
    gemm_kernel<64, false, true><<<(n + 63) / 64, 256, 0, stream>>>(
        cur, nullptr, fc_bf, nullptr, fc_b, nullptr, (float*)d_out, n);
}

// Round 4
// 522.566 us; speedup vs baseline: 1.9105x; 1.2259x over previous
//
#include <hip/hip_runtime.h>

// ---------------------------------------------------------------------------
// GraphConv x3 + FC on MI355X — R4: affine collapse.
// out = x0 K0 + (A x0) K1 + (A^2 x0) K2 + (A^3 x0) K3 + 1 B0 + deg B1 + d2 B2
// K_p (128x64) computed exactly in f32 from layer weights (3 stage kernels),
// aggregation chain y1=Ax0, y2=Ay1, y3=Ay2 in bf16, one K=512 MFMA GEMM.
// d2 = A deg fused into agg pass 1 (int, exact).
// ---------------------------------------------------------------------------

typedef short bf16x8 __attribute__((ext_vector_type(8)));
typedef float f32x4 __attribute__((ext_vector_type(4)));

__device__ inline float bf2f(unsigned short u) {
    union { unsigned int i; float f; } v; v.i = ((unsigned int)u) << 16; return v.f;
}
__device__ inline unsigned short f2bf(float f) {
    union { float f; unsigned int i; } v; v.f = f;
    unsigned int r = v.i + 0x7FFFu + ((v.i >> 16) & 1u);   // RNE
    return (unsigned short)(r >> 16);
}

// ---- prep: stage1 weight products + degree/rank + x f32->bf16 --------------
// blocks [0,64): K0_2[i][j] = sum_k Wo2[k][i]*fcw[j][k]   (matid 0)
//               K1_2[i][j] = sum_k Wr2[k][i]*fcw[j][k]   (matid 1)
// blocks [64, 64+nbe): rank[i] = atomicAdd(&deg[dst[i]],1)
// blocks [64+nbe, ...): x float4 -> 4x bf16
__global__ __launch_bounds__(256) void prep_kernel(
    const float* __restrict__ Wr2, const float* __restrict__ Wo2,
    const float* __restrict__ fcw, float* __restrict__ K0_2, float* __restrict__ K1_2,
    const int* __restrict__ dst, int* __restrict__ deg, int* __restrict__ rank, int e,
    const float* __restrict__ x, unsigned short* __restrict__ xb, int n0q) {
    int b = blockIdx.x, t = threadIdx.x;
    if (b < 64) {
        int matid = b >> 5;
        const float* W = matid ? Wr2 : Wo2;
        float* K = matid ? K1_2 : K0_2;
        int i = t & 127;
        int j = (b & 31) * 2 + (t >> 7);
        float acc = 0.f;
        for (int k = 0; k < 128; k++) acc += W[k * 128 + i] * fcw[j * 128 + k];
        K[i * 64 + j] = acc;
        return;
    }
    b -= 64;
    int nbe = (e + 255) / 256;
    if (b < nbe) {
        int i = b * 256 + t;
        if (i < e) rank[i] = atomicAdd(&deg[dst[i]], 1);
        return;
    }
    b -= nbe;
    int i = b * 256 + t;
    if (i < n0q) {
        float4 v = ((const float4*)x)[i];
        ushort4 o;
        o.x = f2bf(v.x); o.y = f2bf(v.y); o.z = f2bf(v.z); o.w = f2bf(v.w);
        ((ushort4*)xb)[i] = o;
    }
}

// ---- CSR scan --------------------------------------------------------------
__global__ void scan_partial(const int* __restrict__ deg, int* __restrict__ excl,
                             int* __restrict__ bsums, int n) {
    __shared__ int buf[256];
    int t = threadIdx.x, i = blockIdx.x * 256 + t;
    int v = (i < n) ? deg[i] : 0;
    int x = v; buf[t] = v; __syncthreads();
    for (int o = 1; o < 256; o <<= 1) {
        int y = (t >= o) ? buf[t - o] : 0;
        __syncthreads();
        x += y; buf[t] = x;
        __syncthreads();
    }
    if (i < n) excl[i] = x - v;
    if (t == 255) bsums[blockIdx.x] = x;
}

__global__ void scan_bsums(const int* __restrict__ bsums, int* __restrict__ boffs, int nb) {
    __shared__ int buf[512];
    int t = threadIdx.x;
    int v = (t < nb) ? bsums[t] : 0;
    int x = v; buf[t] = v; __syncthreads();
    for (int o = 1; o < 512; o <<= 1) {
        int y = (t >= o) ? buf[t - o] : 0;
        __syncthreads();
        x += y; buf[t] = x;
        __syncthreads();
    }
    if (t < nb) boffs[t] = x - v;
}

__global__ void finalize_scan(const int* __restrict__ excl, const int* __restrict__ boffs,
                              int* __restrict__ start, int n) {
    int i = blockIdx.x * 256 + threadIdx.x;
    if (i < n) start[i] = excl[i] + boffs[blockIdx.x];
}

__global__ void fill_kernel(const int* __restrict__ src, const int* __restrict__ dst,
                            const int* __restrict__ rank, const int* __restrict__ start,
                            int* __restrict__ csr, int e) {
    int i = blockIdx.x * 256 + threadIdx.x;
    if (i < e) csr[start[dst[i]] + rank[i]] = src[i];
}

// ---- stage2: K*_1 from layer-1 (0-based) weights ---------------------------
// matid 0: K0_1 = Wo1^T K0_2 ; 1: K1_1 = Wr1^T K0_2 + Wo1^T K1_2 ; 2: K2_1 = Wr1^T K1_2
__global__ __launch_bounds__(256) void stage2_kernel(
    const float* __restrict__ Wr1, const float* __restrict__ Wo1,
    const float* __restrict__ K0_2, const float* __restrict__ K1_2,
    float* __restrict__ K0_1, float* __restrict__ K1_1, float* __restrict__ K2_1) {
    int b = blockIdx.x, t = threadIdx.x;
    int matid = b >> 5;
    int i = t & 127;
    int j = (b & 31) * 2 + (t >> 7);
    float acc = 0.f;
    if (matid == 0) {
        for (int k = 0; k < 128; k++) acc += Wo1[k * 128 + i] * K0_2[k * 64 + j];
        K0_1[i * 64 + j] = acc;
    } else if (matid == 1) {
        for (int k = 0; k < 128; k++)
            acc += Wr1[k * 128 + i] * K0_2[k * 64 + j] + Wo1[k * 128 + i] * K1_2[k * 64 + j];
        K1_1[i * 64 + j] = acc;
    } else {
        for (int k = 0; k < 128; k++) acc += Wr1[k * 128 + i] * K1_2[k * 64 + j];
        K2_1[i * 64 + j] = acc;
    }
}

// ---- stage3: final K0..K3 packed bf16 + bias vectors -----------------------
// Nw[o*512 + p*128 + i] = bf16(K_p[i][o]);  B0/B1/B2 (f32, 64 each)
__global__ __launch_bounds__(256) void stage3_kernel(
    const float* __restrict__ Wr0, const float* __restrict__ Wo0,
    const float* __restrict__ K0_1, const float* __restrict__ K1_1, const float* __restrict__ K2_1,
    const float* __restrict__ K0_2, const float* __restrict__ K1_2,
    const float* __restrict__ br, const float* __restrict__ fcw, const float* __restrict__ fcb,
    unsigned short* __restrict__ Nw, float* __restrict__ Bv) {
    int b = blockIdx.x, t = threadIdx.x;
    if (b < 128) {
        int matid = b >> 5;
        int i = t & 127;
        int o = (b & 31) * 2 + (t >> 7);
        float acc = 0.f;
        if (matid == 0) {
            for (int k = 0; k < 128; k++) acc += Wo0[k * 128 + i] * K0_1[k * 64 + o];
        } else if (matid == 1) {
            for (int k = 0; k < 128; k++)
                acc += Wr0[k * 128 + i] * K0_1[k * 64 + o] + Wo0[k * 128 + i] * K1_1[k * 64 + o];
        } else if (matid == 2) {
            for (int k = 0; k < 128; k++)
                acc += Wr0[k * 128 + i] * K1_1[k * 64 + o] + Wo0[k * 128 + i] * K2_1[k * 64 + o];
        } else {
            for (int k = 0; k < 128; k++) acc += Wr0[k * 128 + i] * K2_1[k * 64 + o];
        }
        Nw[o * 512 + matid * 128 + i] = f2bf(acc);
        return;
    }
    // bias block: br = b_rel base (3x128), layers 0,1,2
    const float* br0 = br;
    const float* br1 = br + 128;
    const float* br2 = br + 256;
    int j = t & 63;
    int which = t >> 6;
    if (which == 0) {
        float acc = fcb[j];
        for (int k = 0; k < 128; k++) acc += br2[k] * fcw[j * 128 + k];
        for (int k = 0; k < 128; k++) acc += br1[k] * K0_2[k * 64 + j];
        for (int k = 0; k < 128; k++) acc += br0[k] * K0_1[k * 64 + j];
        Bv[j] = acc;                       // B0
    } else if (which == 1) {
        float acc = 0.f;
        for (int k = 0; k < 128; k++) acc += br1[k] * K1_2[k * 64 + j];
        for (int k = 0; k < 128; k++) acc += br0[k] * K1_1[k * 64 + j];
        Bv[64 + j] = acc;                  // B1
    } else if (which == 2) {
        float acc = 0.f;
        for (int k = 0; k < 128; k++) acc += br0[k] * K2_1[k * 64 + j];
        Bv[128 + j] = acc;                 // B2
    }
}

// ---- neighbor aggregation (optionally fused d2 = A deg) --------------------
template <bool D2>
__global__ __launch_bounds__(256) void agg_kernel(
    const unsigned short* __restrict__ xb, const int* __restrict__ csr,
    const int* __restrict__ start, const int* __restrict__ deg,
    unsigned short* __restrict__ aggb, int* __restrict__ d2, int n) {
    int node = blockIdx.x * 4 + (threadIdx.x >> 6);
    if (node >= n) return;
    int lane = threadIdx.x & 63;
    int g    = lane >> 4;
    int fl   = lane & 15;

    int s0 = start[node];
    int d  = deg[node];

    float acc[8];
#pragma unroll
    for (int j = 0; j < 8; j++) acc[j] = 0.f;
    int dsum = 0;

#pragma unroll 4
    for (int e0 = 0; e0 < d; e0 += 4) {
        int idx = e0 + g;
        if (idx < d) {
            int s = csr[s0 + idx];
            bf16x8 v = *(const bf16x8*)(xb + (size_t)s * 128 + fl * 8);
#pragma unroll
            for (int j = 0; j < 8; j++) acc[j] += bf2f((unsigned short)v[j]);
            if (D2 && fl == 0) dsum += deg[s];
        }
    }

#pragma unroll
    for (int j = 0; j < 8; j++) {
        acc[j] += __shfl_xor(acc[j], 16);
        acc[j] += __shfl_xor(acc[j], 32);
    }
    if (D2) {
        dsum += __shfl_xor(dsum, 16);
        dsum += __shfl_xor(dsum, 32);
        if (lane == 0) d2[node] = dsum;
    }

    if (g == 0) {
        bf16x8 o;
#pragma unroll
        for (int j = 0; j < 8; j++) o[j] = (short)f2bf(acc[j]);
        *(bf16x8*)(aggb + (size_t)node * 128 + fl * 8) = o;
    }
}

// ---- final GEMM: out[n,64] = [x0|y1|y2|y3] @ Nw^T + B0 + deg*B1 + d2*B2 ----
__global__ __launch_bounds__(256) void gemm_final(
    const unsigned short* __restrict__ x0, const unsigned short* __restrict__ y1,
    const unsigned short* __restrict__ y2, const unsigned short* __restrict__ y3,
    const unsigned short* __restrict__ Nw, const float* __restrict__ Bv,
    const int* __restrict__ deg, const int* __restrict__ d2,
    float* __restrict__ out, int n) {
    int wave = threadIdx.x >> 6;
    int lane = threadIdx.x & 63;
    int m    = lane & 15;
    int quad = lane >> 4;
    int row0 = blockIdx.x * 64 + wave * 16;
    int arow = row0 + m; if (arow >= n) arow = n - 1;
    size_t abase = (size_t)arow * 128 + quad * 8;

    bf16x8 a[16];
#pragma unroll
    for (int kk2 = 0; kk2 < 4; kk2++) {
        a[0  + kk2] = *(const bf16x8*)(x0 + abase + kk2 * 32);
        a[4  + kk2] = *(const bf16x8*)(y1 + abase + kk2 * 32);
        a[8  + kk2] = *(const bf16x8*)(y2 + abase + kk2 * 32);
        a[12 + kk2] = *(const bf16x8*)(y3 + abase + kk2 * 32);
    }

    // per-lane row scalars for epilogue
    float dg[4], dd[4];
#pragma unroll
    for (int r = 0; r < 4; r++) {
        int orow = row0 + quad * 4 + r;
        int cr = orow < n ? orow : n - 1;
        dg[r] = (float)deg[cr];
        dd[r] = (float)d2[cr];
    }

#pragma unroll
    for (int t = 0; t < 4; t++) {
        int o = t * 16 + m;
        f32x4 acc = {0.f, 0.f, 0.f, 0.f};
#pragma unroll
        for (int kk = 0; kk < 16; kk++) {
            bf16x8 bfr = *(const bf16x8*)(Nw + (size_t)o * 512 + kk * 32 + quad * 8);
            acc = __builtin_amdgcn_mfma_f32_16x16x32_bf16(a[kk], bfr, acc, 0, 0, 0);
        }
        float b0 = Bv[o], b1 = Bv[64 + o], b2 = Bv[128 + o];
#pragma unroll
        for (int r = 0; r < 4; r++) {
            int orow = row0 + quad * 4 + r;
            if (orow < n)
                out[(size_t)orow * 64 + o] = acc[r] + b0 + dg[r] * b1 + dd[r] * b2;
        }
    }
}

// ---------------------------------------------------------------------------
extern "C" void kernel_launch(void* const* d_in, const int* in_sizes, int n_in,
                              void* d_out, int out_size, void* d_ws, size_t ws_size,
                              hipStream_t stream) {
    const float* x      = (const float*)d_in[0];
    const int*   ei     = (const int*)d_in[1];
    const float* W_rel  = (const float*)d_in[2];
    const float* b_rel  = (const float*)d_in[3];
    const float* W_root = (const float*)d_in[4];
    const float* fc_w   = (const float*)d_in[5];
    const float* fc_b   = (const float*)d_in[6];

    const int n = in_sizes[0] / 128;      // 100000
    const int e = in_sizes[1] / 2;        // 1600000
    const int* src = ei;
    const int* dst = ei + e;

    char* p = (char*)d_ws;
    auto take = [&](size_t bytes) -> void* {
        void* r = (void*)p;
        p += (bytes + 255) & ~(size_t)255;
        return r;
    };
    unsigned short* x_bf = (unsigned short*)take((size_t)n * 128 * 2);
    unsigned short* y1   = (unsigned short*)take((size_t)n * 128 * 2);
    unsigned short* y2   = (unsigned short*)take((size_t)n * 128 * 2);
    unsigned short* y3   = (unsigned short*)take((size_t)n * 128 * 2);
    int* deg    = (int*)take((size_t)n * 4);
    int* excl   = (int*)take((size_t)n * 4);
    int* bsums  = (int*)take(512 * 4);
    int* boffs  = (int*)take(512 * 4);
    int* start  = (int*)take((size_t)n * 4);
    int* d2     = (int*)take((size_t)n * 4);
    int* rank   = (int*)take((size_t)e * 4);
    int* csr    = (int*)take((size_t)e * 4);
    float* K0_2 = (float*)take(128 * 64 * 4);
    float* K1_2 = (float*)take(128 * 64 * 4);
    float* K0_1 = (float*)take(128 * 64 * 4);
    float* K1_1 = (float*)take(128 * 64 * 4);
    float* K2_1 = (float*)take(128 * 64 * 4);
    unsigned short* Nw = (unsigned short*)take(64 * 512 * 2);
    float* Bv   = (float*)take(192 * 4);

    const int nb  = (n + 255) / 256;
    const int nbe = (e + 255) / 256;
    const int n0q = n * 128 / 4;
    const int nbx = (n0q + 255) / 256;

    hipMemsetAsync(deg, 0, (size_t)n * 4, stream);
    prep_kernel<<<64 + nbe + nbx, 256, 0, stream>>>(
        W_rel + 2 * 16384, W_root + 2 * 16384, fc_w, K0_2, K1_2,
        dst, deg, rank, e, x, x_bf, n0q);
    scan_partial<<<nb, 256, 0, stream>>>(deg, excl, bsums, n);
    scan_bsums<<<1, 512, 0, stream>>>(bsums, boffs, nb);
    finalize_scan<<<nb, 256, 0, stream>>>(excl, boffs, start, n);
    fill_kernel<<<nbe, 256, 0, stream>>>(src, dst, rank, start, csr, e);
    stage2_kernel<<<96, 256, 0, stream>>>(
        W_rel + 16384, W_root + 16384, K0_2, K1_2, K0_1, K1_1, K2_1);
    stage3_kernel<<<129, 256, 0, stream>>>(
        W_rel, W_root, K0_1, K1_1, K2_1, K0_2, K1_2, b_rel, fc_w, fc_b, Nw, Bv);

    agg_kernel<true ><<<(n + 3) / 4, 256, 0, stream>>>(x_bf, csr, start, deg, y1, d2, n);
    agg_kernel<false><<<(n + 3) / 4, 256, 0, stream>>>(y1,   csr, start, deg, y2, d2, n);
    agg_kernel<false><<<(n + 3) / 4, 256, 0, stream>>>(y2,   csr, start, deg, y3, d2, n);

    gemm_final<<<(n + 63) / 64, 256, 0, stream>>>(
        x_bf, y1, y2, y3, Nw, Bv, deg, d2, (float*)d_out, n);
}